// Round 1
// baseline (473.014 us; speedup 1.0000x reference)
//
#include <hip/hip_runtime.h>
#include <math.h>

#define T_SEQ   2048
#define DMODEL  512
#define NHEADS  8
#define DH      64
#define NEG_INF -1.0e9f

// ---------------------------------------------------------------------------
// GEMM: C[m][n] = sum_k A[m][k] * W[n][k]   (i.e. A @ W^T), M=8192, N=K=512.
// 128x128 tile, BK=32, 256 threads, 8x8 micro-tile split as 2x2 groups of 4x4.
// qkv_scatter=1: write C to (B,H,T,DH) layout; 0: plain row-major (M x 512).
// grid.z picks (Wq,Cq)/(Wk,Ck)/(Wv,Cv).
// ---------------------------------------------------------------------------
__global__ __launch_bounds__(256)
void gemm128_bt(const float* __restrict__ A,
                const float* __restrict__ Wq, const float* __restrict__ Wk,
                const float* __restrict__ Wv,
                float* __restrict__ Cq, float* __restrict__ Ck,
                float* __restrict__ Cv,
                int qkv_scatter)
{
    constexpr int K  = 512;
    constexpr int BK = 32;
    const float* W = (blockIdx.z == 0) ? Wq : (blockIdx.z == 1) ? Wk : Wv;
    float*       C = (blockIdx.z == 0) ? Cq : (blockIdx.z == 1) ? Ck : Cv;

    // pad 132: row stride 528B is 16B-aligned (float4 reads legal), 132%32=4
    // keeps staging stores at 2-way bank aliasing (free on CDNA4).
    __shared__ float As[BK][132];
    __shared__ float Ws[BK][132];

    const int tid = threadIdx.x;
    const int m0 = blockIdx.x * 128;
    const int n0 = blockIdx.y * 128;
    const int tx = tid & 15;
    const int ty = tid >> 4;

    float acc[2][2][4][4];
#pragma unroll
    for (int a = 0; a < 2; ++a)
#pragma unroll
        for (int b = 0; b < 2; ++b)
#pragma unroll
            for (int r = 0; r < 4; ++r)
#pragma unroll
                for (int c = 0; c < 4; ++c) acc[a][b][r][c] = 0.0f;

    const int lr = tid >> 1;          // 0..127 tile row
    const int lc = (tid & 1) * 16;    // k-offset 0 or 16
    const float* ag = A + (size_t)(m0 + lr) * K + lc;
    const float* wg = W + (size_t)(n0 + lr) * K + lc;

    for (int k0 = 0; k0 < K; k0 += BK) {
        float4 av[4], wv4[4];
#pragma unroll
        for (int i = 0; i < 4; ++i) {
            av[i]  = *(const float4*)(ag + k0 + 4 * i);
            wv4[i] = *(const float4*)(wg + k0 + 4 * i);
        }
        __syncthreads();              // previous compute done before restage
#pragma unroll
        for (int i = 0; i < 16; ++i) {
            As[lc + i][lr] = ((const float*)av)[i];
            Ws[lc + i][lr] = ((const float*)wv4)[i];
        }
        __syncthreads();
#pragma unroll
        for (int k = 0; k < BK; ++k) {
            float4 a0 = *(const float4*)&As[k][ty * 4];
            float4 a1 = *(const float4*)&As[k][ty * 4 + 64];
            float4 b0 = *(const float4*)&Ws[k][tx * 4];
            float4 b1 = *(const float4*)&Ws[k][tx * 4 + 64];
            const float ar[2][4] = {{a0.x, a0.y, a0.z, a0.w},
                                    {a1.x, a1.y, a1.z, a1.w}};
            const float bc[2][4] = {{b0.x, b0.y, b0.z, b0.w},
                                    {b1.x, b1.y, b1.z, b1.w}};
#pragma unroll
            for (int rg = 0; rg < 2; ++rg)
#pragma unroll
                for (int cg = 0; cg < 2; ++cg)
#pragma unroll
                    for (int r = 0; r < 4; ++r)
#pragma unroll
                        for (int c = 0; c < 4; ++c)
                            acc[rg][cg][r][c] += ar[rg][r] * bc[cg][c];
        }
    }

#pragma unroll
    for (int rg = 0; rg < 2; ++rg) {
#pragma unroll
        for (int r = 0; r < 4; ++r) {
            const int row = m0 + rg * 64 + ty * 4 + r;
#pragma unroll
            for (int cg = 0; cg < 2; ++cg) {
                const int col = n0 + cg * 64 + tx * 4;
                float4 v = make_float4(acc[rg][cg][r][0], acc[rg][cg][r][1],
                                       acc[rg][cg][r][2], acc[rg][cg][r][3]);
                if (qkv_scatter) {
                    const int b = row >> 11, t = row & 2047;
                    const int h = col >> 6,  d = col & 63;
                    *(float4*)(C + ((size_t)((b * NHEADS + h) * T_SEQ + t) * DH + d)) = v;
                } else {
                    *(float4*)(C + (size_t)row * DMODEL + col) = v;
                }
            }
        }
    }
}

// ---------------------------------------------------------------------------
// Windowed flash attention. One block = one (b,h) x 64-query tile.
// Q,K,V in (B,H,T,DH); output written to (B,T,DMODEL).
// ---------------------------------------------------------------------------
__global__ __launch_bounds__(256)
void attn_kernel(const float* __restrict__ Q, const float* __restrict__ K,
                 const float* __restrict__ V, const float* __restrict__ span_params,
                 float* __restrict__ out)
{
    __shared__ float Qs[DH][68];     // Q^T: [d][row]
    __shared__ float KsPt[DH][68];   // K^T: [d][col] during S; then P^T: [col][row]
    __shared__ float Vs[DH][68];     // V:   [col][d]

    const int tid = threadIdx.x;
    const int bh  = blockIdx.y;
    const int b   = bh >> 3;
    const int h   = bh & 7;
    const int i0  = blockIdx.x * 64;

    const float* Qh = Q + (size_t)bh * T_SEQ * DH;
    const float* Kh = K + (size_t)bh * T_SEQ * DH;
    const float* Vh = V + (size_t)bh * T_SEQ * DH;

    float span = span_params[h];
    span = fminf(fmaxf(span, 0.0f), 1.0f);
    const float eff_span = span * 512.0f;   // MAX_SPAN

    // stage Q tile transposed
    {
        const int r  = tid >> 2;
        const int c0 = (tid & 3) * 16;
        const float* src = Qh + (size_t)(i0 + r) * DH + c0;
        float4 q4[4];
#pragma unroll
        for (int i = 0; i < 4; ++i) q4[i] = ((const float4*)src)[i];
#pragma unroll
        for (int i = 0; i < 16; ++i) Qs[c0 + i][r] = ((const float*)q4)[i];
    }

    const int tx = tid & 15;
    const int ty = tid >> 4;
    float m_row[4], l_row[4], acc[4][4];
#pragma unroll
    for (int r = 0; r < 4; ++r) {
        m_row[r] = -1.0e30f;
        l_row[r] = 0.0f;
#pragma unroll
        for (int c = 0; c < 4; ++c) acc[r][c] = 0.0f;
    }

    const int wspan = (int)(eff_span + 1.0f) + 1;  // conservative window
    int j_lo = i0 - wspan;
    if (j_lo < 0) j_lo = 0;
    j_lo &= ~63;

    for (int j0 = j_lo; j0 <= i0; j0 += 64) {
        __syncthreads();   // A: previous PV reads done before restaging
        {
            const int r  = tid >> 2;
            const int c0 = (tid & 3) * 16;
            const float* ksrc = Kh + (size_t)(j0 + r) * DH + c0;
            const float* vsrc = Vh + (size_t)(j0 + r) * DH + c0;
            float4 k4[4], v4[4];
#pragma unroll
            for (int i = 0; i < 4; ++i) {
                k4[i] = ((const float4*)ksrc)[i];
                v4[i] = ((const float4*)vsrc)[i];
            }
#pragma unroll
            for (int i = 0; i < 16; ++i) KsPt[c0 + i][r] = ((const float*)k4)[i];
#pragma unroll
            for (int i = 0; i < 4; ++i) *(float4*)&Vs[r][c0 + 4 * i] = v4[i];
        }
        __syncthreads();   // B: tiles visible

        // S = Q K^T (4x4 per thread)
        float s[4][4];
#pragma unroll
        for (int r = 0; r < 4; ++r)
#pragma unroll
            for (int c = 0; c < 4; ++c) s[r][c] = 0.0f;
#pragma unroll 16
        for (int k = 0; k < DH; ++k) {
            float4 a  = *(const float4*)&Qs[k][ty * 4];
            float4 bv = *(const float4*)&KsPt[k][tx * 4];
            const float ar[4] = {a.x, a.y, a.z, a.w};
            const float bc[4] = {bv.x, bv.y, bv.z, bv.w};
#pragma unroll
            for (int r = 0; r < 4; ++r)
#pragma unroll
                for (int c = 0; c < 4; ++c) s[r][c] += ar[r] * bc[c];
        }

        // scale + soft-span mask (replicates reference fp32 formula exactly)
#pragma unroll
        for (int r = 0; r < 4; ++r) {
            const int i_g = i0 + ty * 4 + r;
#pragma unroll
            for (int c = 0; c < 4; ++c) {
                const int j_g  = j0 + tx * 4 + c;
                const int dist = i_g - j_g;
                float sv = NEG_INF;
                if (dist >= 0) {
                    float xv = eff_span - (float)dist;
                    float R  = (xv + 1.0f) * 0.25f;       // /4.0 exact
                    R = fminf(fmaxf(R, 0.0f), 1.0f);
                    if (R > 0.0f) sv = s[r][c] * 0.125f + logf(R + 1e-10f);
                }
                s[r][c] = sv;
            }
        }

        // online softmax update (state replicated across the 16-lane tx group)
        float m_new[4], alpha[4], psum[4];
#pragma unroll
        for (int r = 0; r < 4; ++r) {
            float t = fmaxf(fmaxf(s[r][0], s[r][1]), fmaxf(s[r][2], s[r][3]));
#pragma unroll
            for (int off = 1; off < 16; off <<= 1)
                t = fmaxf(t, __shfl_xor(t, off));
            m_new[r] = fmaxf(m_row[r], t);
            alpha[r] = expf(m_row[r] - m_new[r]);
            float ps = 0.0f;
#pragma unroll
            for (int c = 0; c < 4; ++c) {
                float p = expf(s[r][c] - m_new[r]);
                s[r][c] = p;
                ps += p;
            }
#pragma unroll
            for (int off = 1; off < 16; off <<= 1)
                ps += __shfl_xor(ps, off);
            psum[r] = ps;
        }
#pragma unroll
        for (int r = 0; r < 4; ++r) {
            l_row[r] = l_row[r] * alpha[r] + psum[r];
            m_row[r] = m_new[r];
#pragma unroll
            for (int c = 0; c < 4; ++c) acc[r][c] *= alpha[r];
        }

        __syncthreads();   // C: S-loop reads of KsPt done before P^T overwrite
#pragma unroll
        for (int r = 0; r < 4; ++r)
#pragma unroll
            for (int c = 0; c < 4; ++c)
                KsPt[tx * 4 + c][ty * 4 + r] = s[r][c];
        __syncthreads();   // D: P^T visible

        // acc += P V
#pragma unroll 16
        for (int k = 0; k < 64; ++k) {
            float4 p4 = *(const float4*)&KsPt[k][ty * 4];
            float4 v4 = *(const float4*)&Vs[k][tx * 4];
            const float pr[4] = {p4.x, p4.y, p4.z, p4.w};
            const float vc[4] = {v4.x, v4.y, v4.z, v4.w};
#pragma unroll
            for (int r = 0; r < 4; ++r)
#pragma unroll
                for (int c = 0; c < 4; ++c) acc[r][c] += pr[r] * vc[c];
        }
    }

    // write (B,T,DMODEL)
#pragma unroll
    for (int r = 0; r < 4; ++r) {
        const int i_g = i0 + ty * 4 + r;
        const float inv_l = 1.0f / l_row[r];
        float4 o = make_float4(acc[r][0] * inv_l, acc[r][1] * inv_l,
                               acc[r][2] * inv_l, acc[r][3] * inv_l);
        *(float4*)(out + (size_t)(b * T_SEQ + i_g) * DMODEL + h * DH + tx * 4) = o;
    }
}

__global__ void loss_kernel(const float* __restrict__ span_params,
                            float* __restrict__ out_loss)
{
    if (threadIdx.x == 0) {
        float s = 0.0f;
        for (int h = 0; h < NHEADS; ++h)
            s += fminf(fmaxf(span_params[h], 0.0f), 1.0f);
        out_loss[0] = 2e-4f * (s * 0.125f);
    }
}

extern "C" void kernel_launch(void* const* d_in, const int* in_sizes, int n_in,
                              void* d_out, int out_size, void* d_ws, size_t ws_size,
                              hipStream_t stream)
{
    (void)in_sizes; (void)n_in; (void)out_size; (void)ws_size;
    const float* x  = (const float*)d_in[0];
    const float* wq = (const float*)d_in[1];
    const float* wk = (const float*)d_in[2];
    const float* wv = (const float*)d_in[3];
    const float* wo = (const float*)d_in[4];
    const float* sp = (const float*)d_in[5];
    float* out = (float*)d_out;

    const size_t elems = (size_t)4 * T_SEQ * DMODEL;  // 4,194,304
    float* Qb = (float*)d_ws;
    float* Kb = Qb + elems;
    float* Vb = Kb + elems;
    float* Ab = Vb + elems;   // attention output, (B,T,DMODEL)

    // Q,K,V projections (one launch, grid.z = 3)
    gemm128_bt<<<dim3(64, 4, 3), 256, 0, stream>>>(x, wq, wk, wv, Qb, Kb, Vb, 1);
    // windowed flash attention
    attn_kernel<<<dim3(T_SEQ / 64, 32), 256, 0, stream>>>(Qb, Kb, Vb, sp, Ab);
    // output projection
    gemm128_bt<<<dim3(64, 4, 1), 256, 0, stream>>>(Ab, wo, wo, wo, out, out, out, 0);
    // span loss scalar
    loss_kernel<<<1, 64, 0, stream>>>(sp, out + elems);
}

// Round 2
// 294.685 us; speedup vs baseline: 1.6051x; 1.6051x over previous
//
#include <hip/hip_runtime.h>
#include <math.h>

#define T_SEQ   2048
#define DMODEL  512
#define NHEADS  8
#define DH      64
#define NEG_INF -1.0e9f

typedef __attribute__((ext_vector_type(8))) short short8;
typedef __attribute__((ext_vector_type(4))) float f32x4;
typedef unsigned int u32;
typedef unsigned short u16;

__device__ __forceinline__ u16 f2bf(float f) {
    union { float f; u32 u; } w; w.f = f;
    return (u16)((w.u + 0x7fffu + ((w.u >> 16) & 1u)) >> 16);   // RNE
}
__device__ __forceinline__ float bf2f(u16 u) {
    union { u32 u; float f; } w; w.u = ((u32)u) << 16;
    return w.f;
}

// async global->LDS, 16B per lane. LDS dest must be wave-uniform base + lane*16.
__device__ __forceinline__ void async_load16(const u16* g, u16* l) {
    __builtin_amdgcn_global_load_lds(
        (const __attribute__((address_space(1))) u32*)(const void*)g,
        (__attribute__((address_space(3))) u32*)(void*)l, 16, 0, 0);
}

// ---------------------------------------------------------------------------
// fp32 -> bf16 cast, vectorized
// ---------------------------------------------------------------------------
__global__ void cvt_f32_bf16(const float* __restrict__ src,
                             u16* __restrict__ dst, int n4)
{
    int i = blockIdx.x * blockDim.x + threadIdx.x;
    if (i < n4) {
        float4 v = ((const float4*)src)[i];
        ushort4 o;
        o.x = f2bf(v.x); o.y = f2bf(v.y); o.z = f2bf(v.z); o.w = f2bf(v.w);
        ((ushort4*)dst)[i] = o;
    }
}

// ---------------------------------------------------------------------------
// bf16 MFMA GEMM: C[m][n] = sum_k A[m][k]*W[n][k]  (A @ W^T)
// M=8192, N=K=512. 128x128 tile, BK=64, 256 threads = 4 waves (2x2 of 64x64).
// global_load_lds staging with XOR-swizzled source so ds_read_b128 frag loads
// are bank-conflict-free (LDS granule [row][s] holds global k-granule s^(row&7)).
// scatter=1: emit bf16 to (B,H,T,DH); scatter=0: emit fp32 row-major M x 512.
// ---------------------------------------------------------------------------
__global__ __launch_bounds__(256)
void gemm_bf16(const u16* __restrict__ A,
               const u16* __restrict__ W0, const u16* __restrict__ W1,
               const u16* __restrict__ W2,
               u16* __restrict__ Cb0, u16* __restrict__ Cb1,
               u16* __restrict__ Cb2,
               float* __restrict__ Cf, int scatter)
{
    constexpr int K = 512, BK = 64;
    const u16* W  = (blockIdx.z == 0) ? W0 : (blockIdx.z == 1) ? W1 : W2;
    u16*       Cb = (blockIdx.z == 0) ? Cb0 : (blockIdx.z == 1) ? Cb1 : Cb2;

    __shared__ __align__(16) u16 As[128 * BK];   // 16 KB
    __shared__ __align__(16) u16 Bs[128 * BK];   // 16 KB

    const int t    = threadIdx.x;
    const int lane = t & 63;
    const int wave = t >> 6;
    const int wm   = wave >> 1, wn = wave & 1;
    const int m0   = blockIdx.x * 128, n0 = blockIdx.y * 128;

    // staging: thread t, issue i covers LDS linear granule t + 256*i
    //   row = (t>>3) + 32*i, slot = t&7 ; source k-granule = slot ^ (row&7)
    const int srow = t >> 3;
    const int kb   = (t & 7) ^ (srow & 7);
    const u16* gA = A + (size_t)(m0 + srow) * K + kb * 8;
    const u16* gW = W + (size_t)(n0 + srow) * K + kb * 8;

    // fragment LDS offsets (elements). row&7 is it-invariant (tiles step by 16).
    const int rA = wm * 64 + (lane & 15);
    const int rB = wn * 64 + (lane & 15);
    const int kq = lane >> 4;
    const int offA0 = rA * BK + ((kq      ^ (rA & 7)) * 8);
    const int offA1 = rA * BK + (((4 + kq) ^ (rA & 7)) * 8);
    const int offB0 = rB * BK + ((kq      ^ (rB & 7)) * 8);
    const int offB1 = rB * BK + (((4 + kq) ^ (rB & 7)) * 8);

    f32x4 acc[4][4];
#pragma unroll
    for (int it = 0; it < 4; ++it)
#pragma unroll
        for (int jt = 0; jt < 4; ++jt) acc[it][jt] = (f32x4)0.0f;

    for (int k0 = 0; k0 < K; k0 += BK) {
        __syncthreads();                       // prior compute done
#pragma unroll
        for (int i = 0; i < 4; ++i) {
            async_load16(gA + k0 + i * (32 * K), As + t * 8 + i * 2048);
            async_load16(gW + k0 + i * (32 * K), Bs + t * 8 + i * 2048);
        }
        __syncthreads();                       // compiler drains vmcnt before barrier

        short8 af[4][2], bfr[4][2];
#pragma unroll
        for (int it = 0; it < 4; ++it) {
            af[it][0]  = *(const short8*)(As + offA0 + it * 16 * BK);
            af[it][1]  = *(const short8*)(As + offA1 + it * 16 * BK);
            bfr[it][0] = *(const short8*)(Bs + offB0 + it * 16 * BK);
            bfr[it][1] = *(const short8*)(Bs + offB1 + it * 16 * BK);
        }
#pragma unroll
        for (int it = 0; it < 4; ++it)
#pragma unroll
            for (int jt = 0; jt < 4; ++jt) {
                acc[it][jt] = __builtin_amdgcn_mfma_f32_16x16x32_bf16(
                    af[it][0], bfr[jt][0], acc[it][jt], 0, 0, 0);
                acc[it][jt] = __builtin_amdgcn_mfma_f32_16x16x32_bf16(
                    af[it][1], bfr[jt][1], acc[it][jt], 0, 0, 0);
            }
    }

    // epilogue: C/D layout col=lane&15, row=(lane>>4)*4+r  (m89-verified)
    const int r0 = (lane >> 4) * 4;
    const int cl = lane & 15;
#pragma unroll
    for (int it = 0; it < 4; ++it) {
#pragma unroll
        for (int r = 0; r < 4; ++r) {
            const int row = m0 + wm * 64 + it * 16 + r0 + r;
#pragma unroll
            for (int jt = 0; jt < 4; ++jt) {
                const int col = n0 + wn * 64 + jt * 16 + cl;
                const float v = acc[it][jt][r];
                if (scatter) {
                    const int b = row >> 11, tt = row & 2047;
                    const int h = col >> 6,  d = col & 63;
                    Cb[((size_t)((b * NHEADS + h) * T_SEQ + tt)) * DH + d] = f2bf(v);
                } else {
                    Cf[(size_t)row * DMODEL + col] = v;
                }
            }
        }
    }
}

// ---------------------------------------------------------------------------
// Windowed flash attention, fp32 math, bf16 Q/K/V in, bf16 out.
// One block = one (b,h) x 64-query tile.
// ---------------------------------------------------------------------------
__global__ __launch_bounds__(256)
void attn_kernel(const u16* __restrict__ Q, const u16* __restrict__ K,
                 const u16* __restrict__ V, const float* __restrict__ span_params,
                 u16* __restrict__ out)
{
    __shared__ float Qs[DH][68];     // Q^T: [d][row]
    __shared__ float KsPt[DH][68];   // K^T: [d][col] during S; then P^T: [col][row]
    __shared__ float Vs[DH][68];     // V:   [col][d]

    const int tid = threadIdx.x;
    const int bh  = blockIdx.y;
    const int b   = bh >> 3;
    const int h   = bh & 7;
    const int i0  = blockIdx.x * 64;

    const u16* Qh = Q + (size_t)bh * T_SEQ * DH;
    const u16* Kh = K + (size_t)bh * T_SEQ * DH;
    const u16* Vh = V + (size_t)bh * T_SEQ * DH;

    float span = span_params[h];
    span = fminf(fmaxf(span, 0.0f), 1.0f);
    const float eff_span = span * 512.0f;   // MAX_SPAN

    // stage Q tile transposed (16 bf16 per thread)
    {
        const int r  = tid >> 2;
        const int c0 = (tid & 3) * 16;
        const u16* src = Qh + (size_t)(i0 + r) * DH + c0;
        uint4 qa = *(const uint4*)src;
        uint4 qb = *(const uint4*)(src + 8);
        const u32 uu[8] = {qa.x, qa.y, qa.z, qa.w, qb.x, qb.y, qb.z, qb.w};
#pragma unroll
        for (int i = 0; i < 8; ++i) {
            Qs[c0 + 2 * i][r]     = bf2f((u16)(uu[i] & 0xffffu));
            Qs[c0 + 2 * i + 1][r] = bf2f((u16)(uu[i] >> 16));
        }
    }

    const int tx = tid & 15;
    const int ty = tid >> 4;
    float m_row[4], l_row[4], acc[4][4];
#pragma unroll
    for (int r = 0; r < 4; ++r) {
        m_row[r] = -1.0e30f;
        l_row[r] = 0.0f;
#pragma unroll
        for (int c = 0; c < 4; ++c) acc[r][c] = 0.0f;
    }

    const int wspan = (int)(eff_span + 1.0f) + 1;  // conservative window
    int j_lo = i0 - wspan;
    if (j_lo < 0) j_lo = 0;
    j_lo &= ~63;

    for (int j0 = j_lo; j0 <= i0; j0 += 64) {
        __syncthreads();   // A: previous PV reads done before restaging
        {
            const int r  = tid >> 2;
            const int c0 = (tid & 3) * 16;
            const u16* ksrc = Kh + (size_t)(j0 + r) * DH + c0;
            const u16* vsrc = Vh + (size_t)(j0 + r) * DH + c0;
            uint4 ka = *(const uint4*)ksrc;
            uint4 kb4 = *(const uint4*)(ksrc + 8);
            uint4 va = *(const uint4*)vsrc;
            uint4 vb = *(const uint4*)(vsrc + 8);
            const u32 ku[8] = {ka.x, ka.y, ka.z, ka.w, kb4.x, kb4.y, kb4.z, kb4.w};
            const u32 vu[8] = {va.x, va.y, va.z, va.w, vb.x, vb.y, vb.z, vb.w};
#pragma unroll
            for (int i = 0; i < 8; ++i) {
                KsPt[c0 + 2 * i][r]     = bf2f((u16)(ku[i] & 0xffffu));
                KsPt[c0 + 2 * i + 1][r] = bf2f((u16)(ku[i] >> 16));
            }
            float vf[16];
#pragma unroll
            for (int i = 0; i < 8; ++i) {
                vf[2 * i]     = bf2f((u16)(vu[i] & 0xffffu));
                vf[2 * i + 1] = bf2f((u16)(vu[i] >> 16));
            }
#pragma unroll
            for (int i = 0; i < 4; ++i)
                *(float4*)&Vs[r][c0 + 4 * i] =
                    make_float4(vf[4 * i], vf[4 * i + 1], vf[4 * i + 2], vf[4 * i + 3]);
        }
        __syncthreads();   // B: tiles visible

        // S = Q K^T (4x4 per thread)
        float s[4][4];
#pragma unroll
        for (int r = 0; r < 4; ++r)
#pragma unroll
            for (int c = 0; c < 4; ++c) s[r][c] = 0.0f;
#pragma unroll 16
        for (int k = 0; k < DH; ++k) {
            float4 a  = *(const float4*)&Qs[k][ty * 4];
            float4 bv = *(const float4*)&KsPt[k][tx * 4];
            const float ar[4] = {a.x, a.y, a.z, a.w};
            const float bc[4] = {bv.x, bv.y, bv.z, bv.w};
#pragma unroll
            for (int r = 0; r < 4; ++r)
#pragma unroll
                for (int c = 0; c < 4; ++c) s[r][c] += ar[r] * bc[c];
        }

        // scale + soft-span mask (replicates reference fp32 formula)
#pragma unroll
        for (int r = 0; r < 4; ++r) {
            const int i_g = i0 + ty * 4 + r;
#pragma unroll
            for (int c = 0; c < 4; ++c) {
                const int j_g  = j0 + tx * 4 + c;
                const int dist = i_g - j_g;
                float sv = NEG_INF;
                if (dist >= 0) {
                    float xv = eff_span - (float)dist;
                    float R  = (xv + 1.0f) * 0.25f;
                    R = fminf(fmaxf(R, 0.0f), 1.0f);
                    if (R > 0.0f) sv = s[r][c] * 0.125f + logf(R + 1e-10f);
                }
                s[r][c] = sv;
            }
        }

        // online softmax update (state replicated across the 16-lane tx group)
        float m_new[4], alpha[4], psum[4];
#pragma unroll
        for (int r = 0; r < 4; ++r) {
            float t = fmaxf(fmaxf(s[r][0], s[r][1]), fmaxf(s[r][2], s[r][3]));
#pragma unroll
            for (int off = 1; off < 16; off <<= 1)
                t = fmaxf(t, __shfl_xor(t, off));
            m_new[r] = fmaxf(m_row[r], t);
            alpha[r] = expf(m_row[r] - m_new[r]);
            float ps = 0.0f;
#pragma unroll
            for (int c = 0; c < 4; ++c) {
                float p = expf(s[r][c] - m_new[r]);
                s[r][c] = p;
                ps += p;
            }
#pragma unroll
            for (int off = 1; off < 16; off <<= 1)
                ps += __shfl_xor(ps, off);
            psum[r] = ps;
        }
#pragma unroll
        for (int r = 0; r < 4; ++r) {
            l_row[r] = l_row[r] * alpha[r] + psum[r];
            m_row[r] = m_new[r];
#pragma unroll
            for (int c = 0; c < 4; ++c) acc[r][c] *= alpha[r];
        }

        __syncthreads();   // C: S-loop reads of KsPt done before P^T overwrite
#pragma unroll
        for (int r = 0; r < 4; ++r)
#pragma unroll
            for (int c = 0; c < 4; ++c)
                KsPt[tx * 4 + c][ty * 4 + r] = s[r][c];
        __syncthreads();   // D: P^T visible

        // acc += P V
#pragma unroll 16
        for (int k = 0; k < 64; ++k) {
            float4 p4 = *(const float4*)&KsPt[k][ty * 4];
            float4 v4 = *(const float4*)&Vs[k][tx * 4];
            const float pr[4] = {p4.x, p4.y, p4.z, p4.w};
            const float vc[4] = {v4.x, v4.y, v4.z, v4.w};
#pragma unroll
            for (int r = 0; r < 4; ++r)
#pragma unroll
                for (int c = 0; c < 4; ++c) acc[r][c] += pr[r] * vc[c];
        }
    }

    // write bf16 to (B,T,DMODEL)
#pragma unroll
    for (int r = 0; r < 4; ++r) {
        const int i_g = i0 + ty * 4 + r;
        const float inv_l = 1.0f / l_row[r];
        ushort4 o;
        o.x = f2bf(acc[r][0] * inv_l);
        o.y = f2bf(acc[r][1] * inv_l);
        o.z = f2bf(acc[r][2] * inv_l);
        o.w = f2bf(acc[r][3] * inv_l);
        *(ushort4*)(out + (size_t)(b * T_SEQ + i_g) * DMODEL + h * DH + tx * 4) = o;
    }
}

__global__ void loss_kernel(const float* __restrict__ span_params,
                            float* __restrict__ out_loss)
{
    if (threadIdx.x == 0) {
        float s = 0.0f;
        for (int h = 0; h < NHEADS; ++h)
            s += fminf(fmaxf(span_params[h], 0.0f), 1.0f);
        out_loss[0] = 2e-4f * (s * 0.125f);
    }
}

extern "C" void kernel_launch(void* const* d_in, const int* in_sizes, int n_in,
                              void* d_out, int out_size, void* d_ws, size_t ws_size,
                              hipStream_t stream)
{
    (void)in_sizes; (void)n_in; (void)out_size; (void)ws_size;
    const float* x  = (const float*)d_in[0];
    const float* wq = (const float*)d_in[1];
    const float* wk = (const float*)d_in[2];
    const float* wv = (const float*)d_in[3];
    const float* wo = (const float*)d_in[4];
    const float* sp = (const float*)d_in[5];
    float* out = (float*)d_out;

    const size_t elems = (size_t)4 * T_SEQ * DMODEL;  // 4,194,304
    u16* xb  = (u16*)d_ws;
    u16* Qb  = xb + elems;
    u16* Kb  = Qb + elems;
    u16* Vb  = Kb + elems;
    u16* Ab  = Vb + elems;
    u16* wqb = Ab + elems;
    u16* wkb = wqb + 262144;
    u16* wvb = wkb + 262144;
    u16* wob = wvb + 262144;

    // fp32 -> bf16 casts
    cvt_f32_bf16<<<4096, 256, 0, stream>>>(x,  xb,  1048576);
    cvt_f32_bf16<<<256,  256, 0, stream>>>(wq, wqb, 65536);
    cvt_f32_bf16<<<256,  256, 0, stream>>>(wk, wkb, 65536);
    cvt_f32_bf16<<<256,  256, 0, stream>>>(wv, wvb, 65536);
    cvt_f32_bf16<<<256,  256, 0, stream>>>(wo, wob, 65536);

    // Q,K,V projections (bf16 MFMA, one launch, grid.z = 3)
    gemm_bf16<<<dim3(64, 4, 3), 256, 0, stream>>>(
        xb, wqb, wkb, wvb, Qb, Kb, Vb, nullptr, 1);
    // windowed flash attention (fp32 math, bf16 IO)
    attn_kernel<<<dim3(T_SEQ / 64, 32), 256, 0, stream>>>(Qb, Kb, Vb, sp, Ab);
    // output projection (fp32 out)
    gemm_bf16<<<dim3(64, 4, 1), 256, 0, stream>>>(
        Ab, wob, wob, wob, nullptr, nullptr, nullptr, out, 0);
    // span loss scalar
    loss_kernel<<<1, 64, 0, stream>>>(sp, out + elems);
}

// Round 3
// 165.818 us; speedup vs baseline: 2.8526x; 1.7772x over previous
//
#include <hip/hip_runtime.h>
#include <math.h>

#define T_SEQ   2048
#define DMODEL  512
#define NHEADS  8
#define DH      64
#define NEG_INF -1.0e9f

typedef __attribute__((ext_vector_type(8))) short short8;
typedef __attribute__((ext_vector_type(4))) float f32x4;
typedef unsigned int u32;
typedef unsigned short u16;

__device__ __forceinline__ u16 f2bf(float f) {
    union { float f; u32 u; } w; w.f = f;
    return (u16)((w.u + 0x7fffu + ((w.u >> 16) & 1u)) >> 16);   // RNE
}

// async global->LDS, 16B per lane. LDS dest must be wave-uniform base + lane*16.
__device__ __forceinline__ void async_load16(const u16* g, u16* l) {
    __builtin_amdgcn_global_load_lds(
        (const __attribute__((address_space(1))) u32*)(const void*)g,
        (__attribute__((address_space(3))) u32*)(void*)l, 16, 0, 0);
}

// ---------------------------------------------------------------------------
// fused fp32->bf16 casts (x + 4 weights) + span-loss scalar. 5120 blocks.
// ---------------------------------------------------------------------------
__global__ void cast_all(const float* __restrict__ x,  const float* __restrict__ wq,
                         const float* __restrict__ wk, const float* __restrict__ wv,
                         const float* __restrict__ wo, const float* __restrict__ sp,
                         u16* __restrict__ xb,  u16* __restrict__ wqb,
                         u16* __restrict__ wkb, u16* __restrict__ wvb,
                         u16* __restrict__ wob, float* __restrict__ loss_out)
{
    const int bid = blockIdx.x;
    const float* src; u16* dst; int i;
    if (bid < 4096) { src = x; dst = xb; i = bid * 256 + threadIdx.x; }
    else {
        const int wsel = (bid - 4096) >> 8;
        src = (wsel == 0) ? wq : (wsel == 1) ? wk : (wsel == 2) ? wv : wo;
        dst = (wsel == 0) ? wqb : (wsel == 1) ? wkb : (wsel == 2) ? wvb : wob;
        i = ((bid - 4096) & 255) * 256 + threadIdx.x;
    }
    float4 v = ((const float4*)src)[i];
    ushort4 o;
    o.x = f2bf(v.x); o.y = f2bf(v.y); o.z = f2bf(v.z); o.w = f2bf(v.w);
    ((ushort4*)dst)[i] = o;
    if (bid == 5119 && threadIdx.x == 0) {
        float s = 0.0f;
        for (int h = 0; h < NHEADS; ++h)
            s += fminf(fmaxf(sp[h], 0.0f), 1.0f);
        loss_out[0] = 2e-4f * (s * 0.125f);
    }
}

// ---------------------------------------------------------------------------
// bf16 MFMA GEMM: C[m][n] = sum_k A[m][k]*W[n][k]  (A @ W^T)   [unchanged R2]
// ---------------------------------------------------------------------------
__global__ __launch_bounds__(256)
void gemm_bf16(const u16* __restrict__ A,
               const u16* __restrict__ W0, const u16* __restrict__ W1,
               const u16* __restrict__ W2,
               u16* __restrict__ Cb0, u16* __restrict__ Cb1,
               u16* __restrict__ Cb2,
               float* __restrict__ Cf, int scatter)
{
    constexpr int K = 512, BK = 64;
    const u16* W  = (blockIdx.z == 0) ? W0 : (blockIdx.z == 1) ? W1 : W2;
    u16*       Cb = (blockIdx.z == 0) ? Cb0 : (blockIdx.z == 1) ? Cb1 : Cb2;

    __shared__ __align__(16) u16 As[128 * BK];
    __shared__ __align__(16) u16 Bs[128 * BK];

    const int t    = threadIdx.x;
    const int lane = t & 63;
    const int wave = t >> 6;
    const int wm   = wave >> 1, wn = wave & 1;
    const int m0   = blockIdx.x * 128, n0 = blockIdx.y * 128;

    const int srow = t >> 3;
    const int kb   = (t & 7) ^ (srow & 7);
    const u16* gA = A + (size_t)(m0 + srow) * K + kb * 8;
    const u16* gW = W + (size_t)(n0 + srow) * K + kb * 8;

    const int rA = wm * 64 + (lane & 15);
    const int rB = wn * 64 + (lane & 15);
    const int kq = lane >> 4;
    const int offA0 = rA * BK + ((kq      ^ (rA & 7)) * 8);
    const int offA1 = rA * BK + (((4 + kq) ^ (rA & 7)) * 8);
    const int offB0 = rB * BK + ((kq      ^ (rB & 7)) * 8);
    const int offB1 = rB * BK + (((4 + kq) ^ (rB & 7)) * 8);

    f32x4 acc[4][4];
#pragma unroll
    for (int it = 0; it < 4; ++it)
#pragma unroll
        for (int jt = 0; jt < 4; ++jt) acc[it][jt] = (f32x4)0.0f;

    for (int k0 = 0; k0 < K; k0 += BK) {
        __syncthreads();
#pragma unroll
        for (int i = 0; i < 4; ++i) {
            async_load16(gA + k0 + i * (32 * K), As + t * 8 + i * 2048);
            async_load16(gW + k0 + i * (32 * K), Bs + t * 8 + i * 2048);
        }
        __syncthreads();

        short8 af[4][2], bfr[4][2];
#pragma unroll
        for (int it = 0; it < 4; ++it) {
            af[it][0]  = *(const short8*)(As + offA0 + it * 16 * BK);
            af[it][1]  = *(const short8*)(As + offA1 + it * 16 * BK);
            bfr[it][0] = *(const short8*)(Bs + offB0 + it * 16 * BK);
            bfr[it][1] = *(const short8*)(Bs + offB1 + it * 16 * BK);
        }
#pragma unroll
        for (int it = 0; it < 4; ++it)
#pragma unroll
            for (int jt = 0; jt < 4; ++jt) {
                acc[it][jt] = __builtin_amdgcn_mfma_f32_16x16x32_bf16(
                    af[it][0], bfr[jt][0], acc[it][jt], 0, 0, 0);
                acc[it][jt] = __builtin_amdgcn_mfma_f32_16x16x32_bf16(
                    af[it][1], bfr[jt][1], acc[it][jt], 0, 0, 0);
            }
    }

    const int r0 = (lane >> 4) * 4;
    const int cl = lane & 15;
#pragma unroll
    for (int it = 0; it < 4; ++it) {
#pragma unroll
        for (int r = 0; r < 4; ++r) {
            const int row = m0 + wm * 64 + it * 16 + r0 + r;
#pragma unroll
            for (int jt = 0; jt < 4; ++jt) {
                const int col = n0 + wn * 64 + jt * 16 + cl;
                const float v = acc[it][jt][r];
                if (scatter) {
                    const int b = row >> 11, tt = row & 2047;
                    const int h = col >> 6,  d = col & 63;
                    Cb[((size_t)((b * NHEADS + h) * T_SEQ + tt)) * DH + d] = f2bf(v);
                } else {
                    Cf[(size_t)row * DMODEL + col] = v;
                }
            }
        }
    }
}

// ---------------------------------------------------------------------------
// V (B,H,T,DH) -> Vt (B,H,DH,T), bf16, 64x64 LDS tiles.
// ---------------------------------------------------------------------------
__global__ __launch_bounds__(256)
void transpose_v(const u16* __restrict__ V, u16* __restrict__ Vt)
{
    __shared__ u16 tile[64][72];
    const int bh = blockIdx.y;
    const int j0 = blockIdx.x * 64;
    const u16* src = V + (size_t)bh * (T_SEQ * DH) + (size_t)j0 * DH;
    u16* dst = Vt + (size_t)bh * (T_SEQ * DH) + j0;
    const int t = threadIdx.x;
    const int jr = t >> 2, c0 = (t & 3) * 16;
    uint4 a = *(const uint4*)(src + (size_t)jr * DH + c0);
    uint4 b = *(const uint4*)(src + (size_t)jr * DH + c0 + 8);
    *(uint4*)&tile[jr][c0]     = a;
    *(uint4*)&tile[jr][c0 + 8] = b;
    __syncthreads();
    const int d = t >> 2, jc = (t & 3) * 16;
    union { uint4 v; u16 s[8]; } pa, pb;
#pragma unroll
    for (int i = 0; i < 8; ++i) pa.s[i] = tile[jc + i][d];
#pragma unroll
    for (int i = 0; i < 8; ++i) pb.s[i] = tile[jc + 8 + i][d];
    *(uint4*)(dst + (size_t)d * T_SEQ + jc)     = pa.v;
    *(uint4*)(dst + (size_t)d * T_SEQ + jc + 8) = pb.v;
}

// ---------------------------------------------------------------------------
// MFMA windowed flash attention. Block = 4 waves; wave owns 16 queries.
// Q,K in (B,H,T,DH); Vt in (B,H,DH,T); out bf16 (B,T,DMODEL).
// ---------------------------------------------------------------------------
__global__ __launch_bounds__(256)
void attn_mfma(const u16* __restrict__ Q, const u16* __restrict__ K,
               const u16* __restrict__ Vt, const float* __restrict__ span_params,
               u16* __restrict__ out)
{
    __shared__ __align__(16) u16 Ks[64 * 64];      // [j][dh], XOR-swizzled granules
    __shared__ __align__(16) u16 Vs[64 * 64];      // [dh][j], XOR-swizzled granules
    __shared__ __align__(16) u16 Ps[4][16 * 72];   // per-wave P [q][j], pad 72

    const int tid  = threadIdx.x;
    const int lane = tid & 63;
    const int w    = tid >> 6;
    const int nl   = lane & 15;     // C-layout col / frag row-within-16
    const int quad = lane >> 4;
    const int bh   = blockIdx.y;
    const int b    = bh >> 3, h = bh & 7;
    const int i0   = blockIdx.x * 64;
    const int q0   = i0 + w * 16;   // wave's first query

    const u16* Qh = Q  + (size_t)bh * (T_SEQ * DH);
    const u16* Kh = K  + (size_t)bh * (T_SEQ * DH);
    const u16* Vh = Vt + (size_t)bh * (DH * T_SEQ);

    float span = span_params[h];
    span = fminf(fmaxf(span, 0.0f), 1.0f);
    const float eff_span = span * 512.0f;
    const int wspan = (int)(eff_span + 1.0f) + 1;

    // Q A-fragments, held in registers for the whole kernel
    short8 qf0 = *(const short8*)(Qh + (size_t)(q0 + nl) * DH + quad * 8);
    short8 qf1 = *(const short8*)(Qh + (size_t)(q0 + nl) * DH + 32 + quad * 8);

    // staging addresses (same XOR swizzle as gemm; (srow+32)&7 == srow&7)
    const int srow = tid >> 3;
    const int sg   = (tid & 7) ^ (srow & 7);
    const u16* gK = Kh + (size_t)srow * DH + sg * 8;
    const u16* gV = Vh + (size_t)srow * T_SEQ + sg * 8;

    f32x4 o[4];
    float m_r[4], l_r[4];
#pragma unroll
    for (int d = 0; d < 4; ++d) o[d] = (f32x4)0.0f;
#pragma unroll
    for (int r = 0; r < 4; ++r) { m_r[r] = -1.0e30f; l_r[r] = 0.0f; }

    int j_lo = i0 - wspan;
    if (j_lo < 0) j_lo = 0;
    j_lo &= ~63;

    for (int j0 = j_lo; j0 <= i0; j0 += 64) {
        __syncthreads();                 // prior iter's Ks/Vs reads done
        async_load16(gK + (size_t)j0 * DH,            Ks + tid * 8);
        async_load16(gK + (size_t)(j0 + 32) * DH,     Ks + tid * 8 + 2048);
        async_load16(gV + j0,                         Vs + tid * 8);
        async_load16(gV + j0 + (size_t)32 * T_SEQ,    Vs + tid * 8 + 2048);
        __syncthreads();                 // tiles visible (vmcnt drained)

        // ---- S = Q K^T per 16-wide key tile (wave-uniform skip) ----
        f32x4 s[4];
        bool act[4];
#pragma unroll
        for (int n = 0; n < 4; ++n) {
            const int jn = j0 + n * 16;
            act[n] = (jn <= q0 + 15) &&
                     ((float)(q0 - jn - 15) <= eff_span);
            s[n] = (f32x4)0.0f;
            if (act[n]) {
                const int row = n * 16 + nl;
                const u16* kp = Ks + row * 64;
                short8 b0 = *(const short8*)(kp + ((quad ^ (row & 7)) * 8));
                short8 b1 = *(const short8*)(kp + (((4 + quad) ^ (row & 7)) * 8));
                s[n] = __builtin_amdgcn_mfma_f32_16x16x32_bf16(qf0, b0, s[n], 0, 0, 0);
                s[n] = __builtin_amdgcn_mfma_f32_16x16x32_bf16(qf1, b1, s[n], 0, 0, 0);
            }
        }

        // ---- mask + row max ----
        float tmax[4] = {-1.0e30f, -1.0e30f, -1.0e30f, -1.0e30f};
#pragma unroll
        for (int n = 0; n < 4; ++n) {
            if (!act[n]) continue;
            const int jn = j0 + n * 16;
            // tile needs the log(R) edge only if some dist > eff_span-4
            const bool boundary = ((float)(q0 + 15 - jn) > eff_span - 4.0f);
#pragma unroll
            for (int r = 0; r < 4; ++r) {
                const int dist = (q0 + quad * 4 + r) - (jn + nl);
                float sv = NEG_INF;
                if (boundary) {
                    if (dist >= 0) {
                        float xv = eff_span - (float)dist;
                        float R  = fminf(fmaxf((xv + 1.0f) * 0.25f, 0.0f), 1.0f);
                        if (R > 0.0f)
                            sv = s[n][r] * 0.125f +
                                 ((R < 1.0f) ? __logf(R + 1e-10f) : 0.0f);
                    }
                } else {
                    if (dist >= 0) sv = s[n][r] * 0.125f;
                }
                s[n][r] = sv;
                tmax[r] = fmaxf(tmax[r], sv);
            }
        }

        // ---- online softmax state ----
        float alpha[4];
#pragma unroll
        for (int r = 0; r < 4; ++r) {
            float t = tmax[r];
            t = fmaxf(t, __shfl_xor(t, 1));
            t = fmaxf(t, __shfl_xor(t, 2));
            t = fmaxf(t, __shfl_xor(t, 4));
            t = fmaxf(t, __shfl_xor(t, 8));
            const float m_new = fmaxf(m_r[r], t);
            alpha[r] = __expf(m_r[r] - m_new);
            m_r[r] = m_new;
        }

        // ---- P = exp(S - m), write bf16 to per-wave LDS ----
        float psum[4] = {0.0f, 0.0f, 0.0f, 0.0f};
#pragma unroll
        for (int n = 0; n < 4; ++n)
#pragma unroll
            for (int r = 0; r < 4; ++r) {
                const float pv = act[n] ? __expf(s[n][r] - m_r[r]) : 0.0f;
                psum[r] += pv;
                Ps[w][(quad * 4 + r) * 72 + n * 16 + nl] = f2bf(pv);
            }
#pragma unroll
        for (int r = 0; r < 4; ++r) {
            float ps = psum[r];
            ps += __shfl_xor(ps, 1);
            ps += __shfl_xor(ps, 2);
            ps += __shfl_xor(ps, 4);
            ps += __shfl_xor(ps, 8);
            l_r[r] = l_r[r] * alpha[r] + ps;
#pragma unroll
            for (int d = 0; d < 4; ++d) o[d][r] *= alpha[r];
        }

        // ---- O += P V ----
        const bool kf0 = act[0] | act[1];
        const bool kf1 = act[2] | act[3];
        const u16* pb = Ps[w] + nl * 72;
        short8 a0 = *(const short8*)(pb + quad * 8);
        short8 a1 = *(const short8*)(pb + 32 + quad * 8);
#pragma unroll
        for (int d = 0; d < 4; ++d) {
            const int vrow = d * 16 + nl;
            const u16* vp = Vs + vrow * 64;
            if (kf0) {
                short8 vb0 = *(const short8*)(vp + ((quad ^ (vrow & 7)) * 8));
                o[d] = __builtin_amdgcn_mfma_f32_16x16x32_bf16(a0, vb0, o[d], 0, 0, 0);
            }
            if (kf1) {
                short8 vb1 = *(const short8*)(vp + (((4 + quad) ^ (vrow & 7)) * 8));
                o[d] = __builtin_amdgcn_mfma_f32_16x16x32_bf16(a1, vb1, o[d], 0, 0, 0);
            }
        }
    }

    // ---- epilogue ----
#pragma unroll
    for (int r = 0; r < 4; ++r) {
        const int qg = q0 + quad * 4 + r;
        const float inv_l = 1.0f / l_r[r];
        u16* op = out + (size_t)(b * T_SEQ + qg) * DMODEL + h * 64;
#pragma unroll
        for (int d = 0; d < 4; ++d)
            op[d * 16 + nl] = f2bf(o[d][r] * inv_l);
    }
}

extern "C" void kernel_launch(void* const* d_in, const int* in_sizes, int n_in,
                              void* d_out, int out_size, void* d_ws, size_t ws_size,
                              hipStream_t stream)
{
    (void)in_sizes; (void)n_in; (void)out_size; (void)ws_size;
    const float* x  = (const float*)d_in[0];
    const float* wq = (const float*)d_in[1];
    const float* wk = (const float*)d_in[2];
    const float* wv = (const float*)d_in[3];
    const float* wo = (const float*)d_in[4];
    const float* sp = (const float*)d_in[5];
    float* out = (float*)d_out;

    const size_t elems = (size_t)4 * T_SEQ * DMODEL;  // 4,194,304
    u16* xb  = (u16*)d_ws;
    u16* Qb  = xb  + elems;
    u16* Kb  = Qb  + elems;
    u16* Vb  = Kb  + elems;
    u16* Vtb = Vb  + elems;
    u16* Ab  = Vtb + elems;
    u16* wqb = Ab  + elems;
    u16* wkb = wqb + 262144;
    u16* wvb = wkb + 262144;
    u16* wob = wvb + 262144;

    // casts + loss (one launch)
    cast_all<<<5120, 256, 0, stream>>>(x, wq, wk, wv, wo, sp,
                                       xb, wqb, wkb, wvb, wob, out + elems);
    // Q,K,V projections
    gemm_bf16<<<dim3(64, 4, 3), 256, 0, stream>>>(
        xb, wqb, wkb, wvb, Qb, Kb, Vb, nullptr, 1);
    // V -> V^T per head
    transpose_v<<<dim3(32, 32), 256, 0, stream>>>(Vb, Vtb);
    // MFMA windowed flash attention
    attn_mfma<<<dim3(32, 32), 256, 0, stream>>>(Qb, Kb, Vtb, sp, Ab);
    // output projection (fp32 out)
    gemm_bf16<<<dim3(64, 4, 1), 256, 0, stream>>>(
        Ab, wob, wob, wob, nullptr, nullptr, nullptr, out, 0);
}

// Round 4
// 161.006 us; speedup vs baseline: 2.9379x; 1.0299x over previous
//
#include <hip/hip_runtime.h>
#include <math.h>

#define T_SEQ   2048
#define DMODEL  512
#define NHEADS  8
#define DH      64
#define NEG_INF -1.0e9f

typedef __attribute__((ext_vector_type(8))) short short8;
typedef __attribute__((ext_vector_type(4))) float f32x4;
typedef unsigned int u32;
typedef unsigned short u16;

// cheap bf16 pack: round-half-up, error <= 2^-9 rel (same bound as RNE). No NaNs here.
__device__ __forceinline__ u16 f2bf(float f) {
    union { float f; u32 u; } w; w.f = f;
    return (u16)((w.u + 0x8000u) >> 16);
}

// async global->LDS, 16B per lane. LDS dest must be wave-uniform base + lane*16.
__device__ __forceinline__ void async_load16(const u16* g, u16* l) {
    __builtin_amdgcn_global_load_lds(
        (const __attribute__((address_space(1))) u32*)(const void*)g,
        (__attribute__((address_space(3))) u32*)(void*)l, 16, 0, 0);
}

// ---------------------------------------------------------------------------
// fused fp32->bf16 casts (x + 4 weights) + span-loss scalar. 5120 blocks.
// ---------------------------------------------------------------------------
__global__ void cast_all(const float* __restrict__ x,  const float* __restrict__ wq,
                         const float* __restrict__ wk, const float* __restrict__ wv,
                         const float* __restrict__ wo, const float* __restrict__ sp,
                         u16* __restrict__ xb,  u16* __restrict__ wqb,
                         u16* __restrict__ wkb, u16* __restrict__ wvb,
                         u16* __restrict__ wob, float* __restrict__ loss_out)
{
    const int bid = blockIdx.x;
    const float* src; u16* dst; int i;
    if (bid < 4096) { src = x; dst = xb; i = bid * 256 + threadIdx.x; }
    else {
        const int wsel = (bid - 4096) >> 8;
        src = (wsel == 0) ? wq : (wsel == 1) ? wk : (wsel == 2) ? wv : wo;
        dst = (wsel == 0) ? wqb : (wsel == 1) ? wkb : (wsel == 2) ? wvb : wob;
        i = ((bid - 4096) & 255) * 256 + threadIdx.x;
    }
    float4 v = ((const float4*)src)[i];
    ushort4 o;
    o.x = f2bf(v.x); o.y = f2bf(v.y); o.z = f2bf(v.z); o.w = f2bf(v.w);
    ((ushort4*)dst)[i] = o;
    if (bid == 5119 && threadIdx.x == 0) {
        float s = 0.0f;
        for (int h = 0; h < NHEADS; ++h)
            s += fminf(fmaxf(sp[h], 0.0f), 1.0f);
        loss_out[0] = 2e-4f * (s * 0.125f);
    }
}

// ---------------------------------------------------------------------------
// bf16 MFMA GEMM: C[m][n] = sum_k A[m][k]*W[n][k]  (A @ W^T)
// scatter=1: bf16 -> (B,H,T,DH) via LDS-coalesced epilogue; 0: fp32 row-major.
// ---------------------------------------------------------------------------
__global__ __launch_bounds__(256)
void gemm_bf16(const u16* __restrict__ A,
               const u16* __restrict__ W0, const u16* __restrict__ W1,
               const u16* __restrict__ W2,
               u16* __restrict__ Cb0, u16* __restrict__ Cb1,
               u16* __restrict__ Cb2,
               float* __restrict__ Cf, int scatter)
{
    constexpr int K = 512, BK = 64;
    const u16* W  = (blockIdx.z == 0) ? W0 : (blockIdx.z == 1) ? W1 : W2;
    u16*       Cb = (blockIdx.z == 0) ? Cb0 : (blockIdx.z == 1) ? Cb1 : Cb2;

    __shared__ __align__(16) u16 smem[16384];   // 32 KB: As|Bs, reused by epilogue
    u16* As = smem;
    u16* Bs = smem + 8192;

    const int t    = threadIdx.x;
    const int lane = t & 63;
    const int wave = t >> 6;
    const int wm   = wave >> 1, wn = wave & 1;
    const int m0   = blockIdx.x * 128, n0 = blockIdx.y * 128;

    const int srow = t >> 3;
    const int kb   = (t & 7) ^ (srow & 7);
    const u16* gA = A + (size_t)(m0 + srow) * K + kb * 8;
    const u16* gW = W + (size_t)(n0 + srow) * K + kb * 8;

    const int rA = wm * 64 + (lane & 15);
    const int rB = wn * 64 + (lane & 15);
    const int kq = lane >> 4;
    const int offA0 = rA * BK + ((kq      ^ (rA & 7)) * 8);
    const int offA1 = rA * BK + (((4 + kq) ^ (rA & 7)) * 8);
    const int offB0 = rB * BK + ((kq      ^ (rB & 7)) * 8);
    const int offB1 = rB * BK + (((4 + kq) ^ (rB & 7)) * 8);

    f32x4 acc[4][4];
#pragma unroll
    for (int it = 0; it < 4; ++it)
#pragma unroll
        for (int jt = 0; jt < 4; ++jt) acc[it][jt] = (f32x4)0.0f;

    for (int k0 = 0; k0 < K; k0 += BK) {
        __syncthreads();
#pragma unroll
        for (int i = 0; i < 4; ++i) {
            async_load16(gA + k0 + i * (32 * K), As + t * 8 + i * 2048);
            async_load16(gW + k0 + i * (32 * K), Bs + t * 8 + i * 2048);
        }
        __syncthreads();

        short8 af[4][2], bfr[4][2];
#pragma unroll
        for (int it = 0; it < 4; ++it) {
            af[it][0]  = *(const short8*)(As + offA0 + it * 16 * BK);
            af[it][1]  = *(const short8*)(As + offA1 + it * 16 * BK);
            bfr[it][0] = *(const short8*)(Bs + offB0 + it * 16 * BK);
            bfr[it][1] = *(const short8*)(Bs + offB1 + it * 16 * BK);
        }
#pragma unroll
        for (int it = 0; it < 4; ++it)
#pragma unroll
            for (int jt = 0; jt < 4; ++jt) {
                acc[it][jt] = __builtin_amdgcn_mfma_f32_16x16x32_bf16(
                    af[it][0], bfr[jt][0], acc[it][jt], 0, 0, 0);
                acc[it][jt] = __builtin_amdgcn_mfma_f32_16x16x32_bf16(
                    af[it][1], bfr[jt][1], acc[it][jt], 0, 0, 0);
            }
    }

    const int r0 = (lane >> 4) * 4;
    const int cl = lane & 15;

    if (scatter) {
        // two rounds; each stages a 64-row x 128-col bf16 slice (pitch 136) in LDS,
        // then stores coalesced uint4 to (B,H,T,DH).
        constexpr int P = 136;
#pragma unroll
        for (int rnd = 0; rnd < 2; ++rnd) {
            __syncthreads();   // prior use of smem done
#pragma unroll
            for (int s = 0; s < 2; ++s) {
                const int it = rnd * 2 + s;
                const int lrow = wm * 32 + s * 16 + r0;
#pragma unroll
                for (int jt = 0; jt < 4; ++jt) {
                    const int cc = wn * 64 + jt * 16 + cl;
#pragma unroll
                    for (int r = 0; r < 4; ++r)
                        smem[(lrow + r) * P + cc] = f2bf(acc[it][jt][r]);
                }
            }
            __syncthreads();
            const int lrow2 = t >> 2;
            const int h2    = (t >> 1) & 1;
            const int dhalf = t & 1;
            const int grow  = m0 + (lrow2 >> 5) * 64 + rnd * 32 + (lrow2 & 31);
            const int b     = grow >> 11, tt = grow & 2047;
            const int h     = (n0 >> 6) + h2;
            u16* dst = Cb + ((size_t)((b * NHEADS + h) * T_SEQ + tt)) * DH + dhalf * 32;
            const u16* srcl = smem + lrow2 * P + h2 * 64 + dhalf * 32;
#pragma unroll
            for (int i = 0; i < 4; ++i)
                ((uint4*)dst)[i] = *(const uint4*)(srcl + i * 8);
        }
    } else {
#pragma unroll
        for (int it = 0; it < 4; ++it) {
#pragma unroll
            for (int r = 0; r < 4; ++r) {
                const int row = m0 + wm * 64 + it * 16 + r0 + r;
#pragma unroll
                for (int jt = 0; jt < 4; ++jt) {
                    const int col = n0 + wn * 64 + jt * 16 + cl;
                    Cf[(size_t)row * DMODEL + col] = acc[it][jt][r];
                }
            }
        }
    }
}

// ---------------------------------------------------------------------------
// V (B,H,T,DH) -> Vt (B,H,DH,T), bf16, 64x64 LDS tiles.
// ---------------------------------------------------------------------------
__global__ __launch_bounds__(256)
void transpose_v(const u16* __restrict__ V, u16* __restrict__ Vt)
{
    __shared__ u16 tile[64][72];
    const int bh = blockIdx.y;
    const int j0 = blockIdx.x * 64;
    const u16* src = V + (size_t)bh * (T_SEQ * DH) + (size_t)j0 * DH;
    u16* dst = Vt + (size_t)bh * (T_SEQ * DH) + j0;
    const int t = threadIdx.x;
    const int jr = t >> 2, c0 = (t & 3) * 16;
    uint4 a = *(const uint4*)(src + (size_t)jr * DH + c0);
    uint4 b = *(const uint4*)(src + (size_t)jr * DH + c0 + 8);
    *(uint4*)&tile[jr][c0]     = a;
    *(uint4*)&tile[jr][c0 + 8] = b;
    __syncthreads();
    const int d = t >> 2, jc = (t & 3) * 16;
    union { uint4 v; u16 s[8]; } pa, pb;
#pragma unroll
    for (int i = 0; i < 8; ++i) pa.s[i] = tile[jc + i][d];
#pragma unroll
    for (int i = 0; i < 8; ++i) pb.s[i] = tile[jc + 8 + i][d];
    *(uint4*)(dst + (size_t)d * T_SEQ + jc)     = pa.v;
    *(uint4*)(dst + (size_t)d * T_SEQ + jc + 8) = pb.v;
}

// ---------------------------------------------------------------------------
// MFMA windowed flash attention. Block = 2 waves x 16 queries (32 q/block).
// Q,K in (B,H,T,DH); Vt in (B,H,DH,T); out bf16 (B,T,DMODEL).
// ---------------------------------------------------------------------------
__global__ __launch_bounds__(128)
void attn_mfma(const u16* __restrict__ Q, const u16* __restrict__ K,
               const u16* __restrict__ Vt, const float* __restrict__ span_params,
               u16* __restrict__ out)
{
    __shared__ __align__(16) u16 Ks[64 * 64];      // [j][dh], XOR-swizzled granules
    __shared__ __align__(16) u16 Vs[64 * 64];      // [dh][j], XOR-swizzled granules
    __shared__ __align__(16) u16 Ps[2][16 * 76];   // per-wave P [q][j], pitch 76

    const int tid  = threadIdx.x;
    const int lane = tid & 63;
    const int w    = tid >> 6;
    const int nl   = lane & 15;
    const int quad = lane >> 4;
    const int bh   = blockIdx.y;
    const int b    = bh >> 3, h = bh & 7;
    const int i0   = blockIdx.x * 32;
    const int q0   = i0 + w * 16;

    const u16* Qh = Q  + (size_t)bh * (T_SEQ * DH);
    const u16* Kh = K  + (size_t)bh * (T_SEQ * DH);
    const u16* Vh = Vt + (size_t)bh * (DH * T_SEQ);

    float span = span_params[h];
    span = fminf(fmaxf(span, 0.0f), 1.0f);
    const float eff_span = span * 512.0f;
    const int wspan = (int)(eff_span + 1.0f) + 1;

    // Q A-fragments in registers for the whole kernel
    short8 qf0 = *(const short8*)(Qh + (size_t)(q0 + nl) * DH + quad * 8);
    short8 qf1 = *(const short8*)(Qh + (size_t)(q0 + nl) * DH + 32 + quad * 8);

    // staging: 128 threads, 16 rows per issue, 4 issues per buffer
    const int srow = tid >> 3;                     // 0..15
    const int sg   = (tid & 7) ^ (srow & 7);
    const u16* gK = Kh + (size_t)srow * DH + sg * 8;
    const u16* gV = Vh + (size_t)srow * T_SEQ + sg * 8;

    f32x4 o[4];
    float m_r[4], l_r[4];
#pragma unroll
    for (int d = 0; d < 4; ++d) o[d] = (f32x4)0.0f;
#pragma unroll
    for (int r = 0; r < 4; ++r) { m_r[r] = -1.0e30f; l_r[r] = 0.0f; }

    int j_lo = i0 - wspan;
    if (j_lo < 0) j_lo = 0;
    j_lo &= ~63;

    for (int j0 = j_lo; j0 <= i0 + 31; j0 += 64) {
        __syncthreads();
#pragma unroll
        for (int i = 0; i < 4; ++i) {
            async_load16(gK + (size_t)(j0 + i * 16) * DH, Ks + tid * 8 + i * 1024);
            async_load16(gV + j0 + (size_t)(i * 16) * T_SEQ, Vs + tid * 8 + i * 1024);
        }
        __syncthreads();

        // ---- S = Q K^T per 16-wide key tile ----
        f32x4 s[4];
        bool any[4];
#pragma unroll
        for (int n = 0; n < 4; ++n) {
            const int jn = j0 + n * 16;
            any[n] = (jn <= q0 + 15) &&
                     ((float)(q0 - jn - 15) < eff_span + 1.0f);   // R>0 exists
            s[n] = (f32x4)0.0f;
            if (any[n]) {
                const int row = n * 16 + nl;
                const u16* kp = Ks + row * 64;
                short8 b0 = *(const short8*)(kp + ((quad ^ (row & 7)) * 8));
                short8 b1 = *(const short8*)(kp + (((4 + quad) ^ (row & 7)) * 8));
                s[n] = __builtin_amdgcn_mfma_f32_16x16x32_bf16(qf0, b0, s[n], 0, 0, 0);
                s[n] = __builtin_amdgcn_mfma_f32_16x16x32_bf16(qf1, b1, s[n], 0, 0, 0);
            }
        }

        // ---- mask + row max, 3-way tile classification (wave-uniform) ----
        float tmax[4] = {-1.0e30f, -1.0e30f, -1.0e30f, -1.0e30f};
#pragma unroll
        for (int n = 0; n < 4; ++n) {
            if (!any[n]) continue;
            const int jn = j0 + n * 16;
            const bool causal_b = (jn + 15 > q0);                           // some dist<0
            const bool span_b   = ((float)(q0 + 15 - jn) > eff_span - 3.0f); // some R<1
            if (!causal_b && !span_b) {
#pragma unroll
                for (int r = 0; r < 4; ++r) {
                    const float sv = s[n][r] * 0.125f;
                    s[n][r] = sv;
                    tmax[r] = fmaxf(tmax[r], sv);
                }
            } else if (!span_b) {
#pragma unroll
                for (int r = 0; r < 4; ++r) {
                    const int dist = (q0 + quad * 4 + r) - (jn + nl);
                    const float sv = (dist >= 0) ? s[n][r] * 0.125f : NEG_INF;
                    s[n][r] = sv;
                    tmax[r] = fmaxf(tmax[r], sv);
                }
            } else {
#pragma unroll
                for (int r = 0; r < 4; ++r) {
                    const int dist = (q0 + quad * 4 + r) - (jn + nl);
                    float sv = NEG_INF;
                    if (dist >= 0) {
                        float xv = eff_span - (float)dist;
                        float R  = fminf(fmaxf((xv + 1.0f) * 0.25f, 0.0f), 1.0f);
                        if (R > 0.0f)
                            sv = s[n][r] * 0.125f +
                                 ((R < 1.0f) ? __logf(R + 1e-10f) : 0.0f);
                    }
                    s[n][r] = sv;
                    tmax[r] = fmaxf(tmax[r], sv);
                }
            }
        }

        // ---- online softmax state ----
        float alpha[4];
#pragma unroll
        for (int r = 0; r < 4; ++r) {
            float t = tmax[r];
            t = fmaxf(t, __shfl_xor(t, 1));
            t = fmaxf(t, __shfl_xor(t, 2));
            t = fmaxf(t, __shfl_xor(t, 4));
            t = fmaxf(t, __shfl_xor(t, 8));
            const float m_new = fmaxf(m_r[r], t);
            alpha[r] = __expf(m_r[r] - m_new);
            m_r[r] = m_new;
        }

        // ---- P = exp(S - m) -> bf16 LDS ----
        float psum[4] = {0.0f, 0.0f, 0.0f, 0.0f};
#pragma unroll
        for (int n = 0; n < 4; ++n) {
            if (any[n]) {
#pragma unroll
                for (int r = 0; r < 4; ++r) {
                    const float pv = __expf(s[n][r] - m_r[r]);
                    psum[r] += pv;
                    Ps[w][(quad * 4 + r) * 76 + n * 16 + nl] = f2bf(pv);
                }
            } else {
#pragma unroll
                for (int r = 0; r < 4; ++r)
                    Ps[w][(quad * 4 + r) * 76 + n * 16 + nl] = 0;
            }
        }
#pragma unroll
        for (int r = 0; r < 4; ++r) {
            float ps = psum[r];
            ps += __shfl_xor(ps, 1);
            ps += __shfl_xor(ps, 2);
            ps += __shfl_xor(ps, 4);
            ps += __shfl_xor(ps, 8);
            l_r[r] = l_r[r] * alpha[r] + ps;
#pragma unroll
            for (int d = 0; d < 4; ++d) o[d][r] *= alpha[r];
        }

        // ---- O += P V ----
        const bool kf0 = any[0] | any[1];
        const bool kf1 = any[2] | any[3];
        const u16* pb = Ps[w] + nl * 76;
        short8 a0 = *(const short8*)(pb + quad * 8);
        short8 a1 = *(const short8*)(pb + 32 + quad * 8);
#pragma unroll
        for (int d = 0; d < 4; ++d) {
            const int vrow = d * 16 + nl;
            const u16* vp = Vs + vrow * 64;
            if (kf0) {
                short8 vb0 = *(const short8*)(vp + ((quad ^ (vrow & 7)) * 8));
                o[d] = __builtin_amdgcn_mfma_f32_16x16x32_bf16(a0, vb0, o[d], 0, 0, 0);
            }
            if (kf1) {
                short8 vb1 = *(const short8*)(vp + (((4 + quad) ^ (vrow & 7)) * 8));
                o[d] = __builtin_amdgcn_mfma_f32_16x16x32_bf16(a1, vb1, o[d], 0, 0, 0);
            }
        }
    }

    // ---- epilogue ----
#pragma unroll
    for (int r = 0; r < 4; ++r) {
        const int qg = q0 + quad * 4 + r;
        const float inv_l = 1.0f / l_r[r];
        u16* op = out + (size_t)(b * T_SEQ + qg) * DMODEL + h * 64;
#pragma unroll
        for (int d = 0; d < 4; ++d)
            op[d * 16 + nl] = f2bf(o[d][r] * inv_l);
    }
}

extern "C" void kernel_launch(void* const* d_in, const int* in_sizes, int n_in,
                              void* d_out, int out_size, void* d_ws, size_t ws_size,
                              hipStream_t stream)
{
    (void)in_sizes; (void)n_in; (void)out_size; (void)ws_size;
    const float* x  = (const float*)d_in[0];
    const float* wq = (const float*)d_in[1];
    const float* wk = (const float*)d_in[2];
    const float* wv = (const float*)d_in[3];
    const float* wo = (const float*)d_in[4];
    const float* sp = (const float*)d_in[5];
    float* out = (float*)d_out;

    const size_t elems = (size_t)4 * T_SEQ * DMODEL;  // 4,194,304
    u16* xb  = (u16*)d_ws;
    u16* Qb  = xb  + elems;
    u16* Kb  = Qb  + elems;
    u16* Vb  = Kb  + elems;
    u16* Vtb = Vb  + elems;
    u16* Ab  = Vtb + elems;
    u16* wqb = Ab  + elems;
    u16* wkb = wqb + 262144;
    u16* wvb = wkb + 262144;
    u16* wob = wvb + 262144;

    // casts + loss (one launch)
    cast_all<<<5120, 256, 0, stream>>>(x, wq, wk, wv, wo, sp,
                                       xb, wqb, wkb, wvb, wob, out + elems);
    // Q,K,V projections
    gemm_bf16<<<dim3(64, 4, 3), 256, 0, stream>>>(
        xb, wqb, wkb, wvb, Qb, Kb, Vb, nullptr, 1);
    // V -> V^T per head
    transpose_v<<<dim3(32, 32), 256, 0, stream>>>(Vb, Vtb);
    // MFMA windowed flash attention (32 q / block)
    attn_mfma<<<dim3(64, 32), 128, 0, stream>>>(Qb, Kb, Vtb, sp, Ab);
    // output projection (fp32 out)
    gemm_bf16<<<dim3(64, 4, 1), 256, 0, stream>>>(
        Ab, wob, wob, wob, nullptr, nullptr, nullptr, out, 0);
}